// Round 1
// baseline (610.380 us; speedup 1.0000x reference)
//
#include <hip/hip_runtime.h>

// GraphAttention (e3nn-style) on MI355X.
// Dims: M0=16 M1=8 Q0=8 Q1=4 O0=16 O1=8 EDGE_BASIS=16 HIDDEN=32
// TPK numel=320 (offs 0,128,192,256,288), TPV numel=640 (offs 0,256,384,512,576)
//
// Structure:
//  node_pre : per-node q = x@Wq, qd = q@wdot (folded), zero z/U accumulators,
//             plus a one-thread probe of edge_index layout (int32 vs int64).
//  edge_kernel (1 thread = 1 edge, BS=64):
//             hk=silu(es@W1k/4); tensor-product contractions with W2 columns
//             read as wave-uniform scalar loads; dot with qd[recv]; then
//             atomics: z[r]+=exp(dot), U[r]+=exp(dot/2)*v  (softmax factored:
//             a=sqrt(ex/z)=exp(dot/2)/sqrt(z)).
//  finalize : out = z>0 ? U*rsqrt(z) : 0.
//
// ws layout (floats): qd[N*20] | z[N] | U[N*40] | flag(1 int)

#define BS 64

__device__ __forceinline__ float silu_f(float x) {
    return x * (1.0f / (1.0f + __expf(-x)));
}

__global__ __launch_bounds__(256) void node_pre(
    const float* __restrict__ node_ft,
    const int*   __restrict__ ei,
    const float* __restrict__ w_q_s,   // [16,8]
    const float* __restrict__ w_q_v,   // [8,4]
    const float* __restrict__ wdot_s,  // [8,8]
    const float* __restrict__ wdot_v,  // [4,4]
    float* __restrict__ qd,            // [N,20]
    float* __restrict__ zbuf,          // [N]
    float* __restrict__ U,             // [N,40]
    int*   __restrict__ flag,
    int N, int E)
{
    const int n = blockIdx.x * blockDim.x + threadIdx.x;
    if (n == 0) {
        // Probe edge_index element width: int64 layout => every odd 32-bit word
        // (high half of a value < N) is zero. Random int32 data: OR != 0 w.p. ~1.
        int acc = 0;
        const int kmax = (E < 64) ? E : 64;
        for (int k = 0; k < kmax; ++k) acc |= ei[2*k + 1];
        *flag = (acc == 0) ? 1 : 0;
    }
    if (n >= N) return;

    const float* nf = node_ft + (size_t)n * 40;
    float xs[16];
#pragma unroll
    for (int i = 0; i < 16; ++i) xs[i] = nf[i];

    float q[8];
#pragma unroll
    for (int o = 0; o < 8; ++o) {
        float a = 0.f;
#pragma unroll
        for (int i = 0; i < 16; ++i) a += xs[i] * w_q_s[i*8 + o];
        q[o] = a * 0.25f;                       // 1/sqrt(16)
    }
    float* qdn = qd + (size_t)n * 20;
#pragma unroll
    for (int j = 0; j < 8; ++j) {
        float a = 0.f;
#pragma unroll
        for (int i = 0; i < 8; ++i) a += q[i] * wdot_s[i*8 + j];
        qdn[j] = a;
    }

    float xv[8][3];
#pragma unroll
    for (int i = 0; i < 8; ++i)
#pragma unroll
        for (int c = 0; c < 3; ++c) xv[i][c] = nf[16 + i*3 + c];

    float qv[4][3];
#pragma unroll
    for (int o = 0; o < 4; ++o)
#pragma unroll
        for (int c = 0; c < 3; ++c) {
            float a = 0.f;
#pragma unroll
            for (int i = 0; i < 8; ++i) a += xv[i][c] * w_q_v[i*4 + o];
            qv[o][c] = a * 0.35355339059327379f;  // 1/sqrt(8)
        }
#pragma unroll
    for (int j = 0; j < 4; ++j)
#pragma unroll
        for (int c = 0; c < 3; ++c) {
            float a = 0.f;
#pragma unroll
            for (int i = 0; i < 4; ++i) a += qv[i][c] * wdot_v[i*4 + j];
            qdn[8 + j*3 + c] = a;
        }

    zbuf[n] = 0.f;
    float* un = U + (size_t)n * 40;
#pragma unroll
    for (int k = 0; k < 40; ++k) un[k] = 0.f;
}

__global__ __launch_bounds__(BS) void edge_kernel(
    const float* __restrict__ node_ft,
    const int*   __restrict__ ei,
    const float* __restrict__ edge_sh,      // [E,4]
    const float* __restrict__ edge_scalars, // [E,16]
    const float* __restrict__ fck_w1,       // [16,32]
    const float* __restrict__ fck_w2,       // [32,320]
    const float* __restrict__ fcv_w1,       // [16,32]
    const float* __restrict__ fcv_w2,       // [32,640]
    const float* __restrict__ qd,           // [N,20]
    float* __restrict__ zbuf,
    float* __restrict__ U,
    const int* __restrict__ flag,
    int N, int E)
{
    // LDS = dynamically-indexable private storage (lane-consecutive columns,
    // conflict-free); h stays in VGPRs (j loops fully unrolled).
    __shared__ float s_xs[16][BS];
    __shared__ float s_xv[3][8][BS];
    __shared__ float s_pvv[8][BS];

    const int tid = threadIdx.x;
    const int e = blockIdx.x * BS + tid;
    if (e >= E) return;

    const int is64 = *flag;
    const int snd = is64 ? ei[2*e]       : ei[e];
    const int rcv = is64 ? ei[2*(E + e)] : ei[E + e];

    const float4 sh4 = *(const float4*)(edge_sh + (size_t)e * 4);
    const float shs = sh4.x;
    const float shv_[3] = {sh4.y, sh4.z, sh4.w};

    // gather sender features -> LDS
    {
        const float4* nf4 = (const float4*)(node_ft + (size_t)snd * 40);
        float xb[40];
#pragma unroll
        for (int t = 0; t < 10; ++t) {
            const float4 v = nf4[t];
            xb[4*t+0] = v.x; xb[4*t+1] = v.y; xb[4*t+2] = v.z; xb[4*t+3] = v.w;
        }
#pragma unroll
        for (int i = 0; i < 16; ++i) s_xs[i][tid] = xb[i];
#pragma unroll
        for (int i = 0; i < 8; ++i) {
            const float a = xb[16 + i*3 + 0];
            const float b = xb[16 + i*3 + 1];
            const float c = xb[16 + i*3 + 2];
            s_xv[0][i][tid] = a; s_xv[1][i][tid] = b; s_xv[2][i][tid] = c;
            s_pvv[i][tid] = (a*shv_[0] + b*shv_[1] + c*shv_[2]) * 0.57735026918962576f;
        }
    }

    float es[16];
    {
        const float4* esp = (const float4*)(edge_scalars + (size_t)e * 16);
#pragma unroll
        for (int t = 0; t < 4; ++t) {
            const float4 v = esp[t];
            es[4*t+0] = v.x; es[4*t+1] = v.y; es[4*t+2] = v.z; es[4*t+3] = v.w;
        }
    }

    // ================= K side =================
    float hk[32];
#pragma unroll
    for (int j = 0; j < 32; ++j) {
        float a = 0.f;
#pragma unroll
        for (int t = 0; t < 16; ++t) a += es[t] * fck_w1[t*32 + j];
        hk[j] = silu_f(a * 0.25f);
    }

    float tk1[8] = {}, tk3[4] = {};
#pragma unroll 1
    for (int i = 0; i < 16; ++i) {
        float w1[8] = {}, w3[4] = {};
#pragma unroll
        for (int j = 0; j < 32; ++j) {
            const float hj = hk[j];
            const float* Wr = fck_w2 + j*320;
#pragma unroll
            for (int o = 0; o < 8; ++o) w1[o] += hj * Wr[i*8 + o];
#pragma unroll
            for (int o = 0; o < 4; ++o) w3[o] += hj * Wr[192 + i*4 + o];
        }
        const float p = s_xs[i][tid];
#pragma unroll
        for (int o = 0; o < 8; ++o) tk1[o] += p * w1[o];
#pragma unroll
        for (int o = 0; o < 4; ++o) tk3[o] += p * w3[o];
    }

    float tk2[8] = {};
#pragma unroll 1
    for (int i = 0; i < 8; ++i) {
        float w2[8] = {};
#pragma unroll
        for (int j = 0; j < 32; ++j) {
            const float hj = hk[j];
            const float* Wr = fck_w2 + j*320;
#pragma unroll
            for (int o = 0; o < 8; ++o) w2[o] += hj * Wr[128 + i*8 + o];
        }
        const float p = s_pvv[i][tid];
#pragma unroll
        for (int o = 0; o < 8; ++o) tk2[o] += p * w2[o];
    }

    float tk4[4][3] = {}, tk5[4][3] = {};
#pragma unroll 1
    for (int i = 0; i < 8; ++i) {
        float w4[4] = {}, w5[4] = {};
#pragma unroll
        for (int j = 0; j < 32; ++j) {
            const float hj = hk[j];
            const float* Wr = fck_w2 + j*320;
#pragma unroll
            for (int o = 0; o < 4; ++o) w4[o] += hj * Wr[256 + i*4 + o];
#pragma unroll
            for (int o = 0; o < 4; ++o) w5[o] += hj * Wr[288 + i*4 + o];
        }
        const float x0 = s_xv[0][i][tid];
        const float x1 = s_xv[1][i][tid];
        const float x2 = s_xv[2][i][tid];
#pragma unroll
        for (int o = 0; o < 4; ++o) {
            tk4[o][0] += x0*w4[o]; tk4[o][1] += x1*w4[o]; tk4[o][2] += x2*w4[o];
            tk5[o][0] += x0*w5[o]; tk5[o][1] += x1*w5[o]; tk5[o][2] += x2*w5[o];
        }
    }

    // dot with qd[recv]; scales folded:
    //  CS = 1/sqrt(32)/sqrt(24)/sqrt(80), CV = (1/32)*(1/sqrt3)/sqrt(80)
    float qdr[20];
    {
        const float4* qp = (const float4*)(qd + (size_t)rcv * 20);
#pragma unroll
        for (int t = 0; t < 5; ++t) {
            const float4 v = qp[t];
            qdr[4*t+0] = v.x; qdr[4*t+1] = v.y; qdr[4*t+2] = v.z; qdr[4*t+3] = v.w;
        }
    }
    float dots = 0.f, dotv = 0.f;
#pragma unroll
    for (int o = 0; o < 8; ++o) dots += qdr[o] * (shs*tk1[o] + tk2[o]);
#pragma unroll
    for (int o = 0; o < 4; ++o)
#pragma unroll
        for (int c = 0; c < 3; ++c) {
            const int c1 = (c+1) % 3, c2 = (c+2) % 3;
            const float kv = tk3[o]*shv_[c] + shs*tk4[o][c]
                + (shv_[c2]*tk5[o][c1] - shv_[c1]*tk5[o][c2]) * 0.70710678118654752f;
            dotv += qdr[8 + o*3 + c] * kv;
        }
    const float dot = dots * 4.0343567508008e-3f + dotv * 2.0171788261497e-3f;

    const float sa = __expf(0.5f * dot);   // sqrt(exp(dot))
    const float ex = sa * sa;              // exp(dot)
    atomicAdd(zbuf + rcv, ex);

    // ================= V side =================
    float hv[32];
#pragma unroll
    for (int j = 0; j < 32; ++j) {
        float a = 0.f;
#pragma unroll
        for (int t = 0; t < 16; ++t) a += es[t] * fcv_w1[t*32 + j];
        hv[j] = silu_f(a * 0.25f);
    }

    float tv1[16] = {}, tv3[8] = {};
#pragma unroll 1
    for (int i = 0; i < 16; ++i) {
        float w1[16] = {}, w3[8] = {};
#pragma unroll
        for (int j = 0; j < 32; ++j) {
            const float hj = hv[j];
            const float* Wr = fcv_w2 + j*640;
#pragma unroll
            for (int o = 0; o < 16; ++o) w1[o] += hj * Wr[i*16 + o];
#pragma unroll
            for (int o = 0; o < 8; ++o)  w3[o] += hj * Wr[384 + i*8 + o];
        }
        const float p = s_xs[i][tid];
#pragma unroll
        for (int o = 0; o < 16; ++o) tv1[o] += p * w1[o];
#pragma unroll
        for (int o = 0; o < 8; ++o)  tv3[o] += p * w3[o];
    }

    float tv2[16] = {};
#pragma unroll 1
    for (int i = 0; i < 8; ++i) {
        float w2[16] = {};
#pragma unroll
        for (int j = 0; j < 32; ++j) {
            const float hj = hv[j];
            const float* Wr = fcv_w2 + j*640;
#pragma unroll
            for (int o = 0; o < 16; ++o) w2[o] += hj * Wr[256 + i*16 + o];
        }
        const float p = s_pvv[i][tid];
#pragma unroll
        for (int o = 0; o < 16; ++o) tv2[o] += p * w2[o];
    }

    float tv4[8][3] = {}, tv5[8][3] = {};
#pragma unroll 1
    for (int i = 0; i < 8; ++i) {
        float w4[8] = {}, w5[8] = {};
#pragma unroll
        for (int j = 0; j < 32; ++j) {
            const float hj = hv[j];
            const float* Wr = fcv_w2 + j*640;
#pragma unroll
            for (int o = 0; o < 8; ++o) w4[o] += hj * Wr[512 + i*8 + o];
#pragma unroll
            for (int o = 0; o < 8; ++o) w5[o] += hj * Wr[576 + i*8 + o];
        }
        const float x0 = s_xv[0][i][tid];
        const float x1 = s_xv[1][i][tid];
        const float x2 = s_xv[2][i][tid];
#pragma unroll
        for (int o = 0; o < 8; ++o) {
            tv4[o][0] += x0*w4[o]; tv4[o][1] += x1*w4[o]; tv4[o][2] += x2*w4[o];
            tv5[o][0] += x0*w5[o]; tv5[o][1] += x1*w5[o]; tv5[o][2] += x2*w5[o];
        }
    }

    float* Ur = U + (size_t)rcv * 40;
    const float cs_out = 0.03608439182435161f;   // (1/sqrt32)*(1/sqrt24)
#pragma unroll
    for (int o = 0; o < 16; ++o) {
        const float vs = (shs*tv1[o] + tv2[o]) * cs_out;
        atomicAdd(Ur + o, sa * vs);
    }
#pragma unroll
    for (int o = 0; o < 8; ++o)
#pragma unroll
        for (int c = 0; c < 3; ++c) {
            const int c1 = (c+1) % 3, c2 = (c+2) % 3;
            const float vv = (tv3[o]*shv_[c] + shs*tv4[o][c]
                + (shv_[c2]*tv5[o][c1] - shv_[c1]*tv5[o][c2]) * 0.70710678118654752f)
                * 0.03125f;                      // (1/sqrt32)*(1/sqrt32)
            atomicAdd(Ur + 16 + o*3 + c, sa * vv);
        }
}

__global__ __launch_bounds__(256) void finalize(
    const float* __restrict__ zbuf,
    const float* __restrict__ U,
    float* __restrict__ out, int N)
{
    const int idx = blockIdx.x * blockDim.x + threadIdx.x;
    if (idx >= N * 40) return;
    const int n = idx / 40;
    const float zn = zbuf[n];
    out[idx] = (zn > 0.f) ? U[idx] * rsqrtf(zn) : 0.f;
}

extern "C" void kernel_launch(void* const* d_in, const int* in_sizes, int n_in,
                              void* d_out, int out_size, void* d_ws, size_t ws_size,
                              hipStream_t stream) {
    const float* node_ft      = (const float*)d_in[0];
    const int*   edge_index   = (const int*)  d_in[1];
    const float* edge_sh      = (const float*)d_in[2];
    const float* edge_scalars = (const float*)d_in[3];
    const float* w_q_s        = (const float*)d_in[4];
    const float* w_q_v        = (const float*)d_in[5];
    const float* fck_w1       = (const float*)d_in[6];
    const float* fck_w2       = (const float*)d_in[7];
    const float* fcv_w1       = (const float*)d_in[8];
    const float* fcv_w2       = (const float*)d_in[9];
    const float* wdot_s       = (const float*)d_in[10];
    const float* wdot_v       = (const float*)d_in[11];

    const int N = in_sizes[0] / 40;   // node_ft [N, 40]
    const int E = in_sizes[2] / 4;    // edge_sh [E, 4]

    float* ws  = (float*)d_ws;
    float* qd  = ws;                      // N*20
    float* z   = ws + (size_t)N * 20;     // N
    float* U   = z + N;                   // N*40
    int*   flg = (int*)(U + (size_t)N * 40);

    float* out = (float*)d_out;

    hipLaunchKernelGGL(node_pre, dim3((N + 255) / 256), dim3(256), 0, stream,
                       node_ft, edge_index, w_q_s, w_q_v, wdot_s, wdot_v,
                       qd, z, U, flg, N, E);
    hipLaunchKernelGGL(edge_kernel, dim3((E + BS - 1) / BS), dim3(BS), 0, stream,
                       node_ft, edge_index, edge_sh, edge_scalars,
                       fck_w1, fck_w2, fcv_w1, fcv_w2,
                       qd, z, U, flg, N, E);
    hipLaunchKernelGGL(finalize, dim3((N * 40 + 255) / 256), dim3(256), 0, stream,
                       z, U, out, N);
}